// Round 12
// baseline (322.547 us; speedup 1.0000x reference)
//
#include <hip/hip_runtime.h>
#include <hip/hip_bf16.h>
#include <math.h>

#define L2E 1.4426950408889634f
#define T_STEPS 8192
#define KTOT 5104   // 8 channels * 638 spatial (22*29)
#define EPS_LTC 1e-8f
#define KP 5120     // permuted/padded K (160 chunks x 32)

// scan chunking: 1024 chunks x 8 steps, 16-step burn-in (chunks 0,1 exact).
#define SCAN_CHUNKS 1024
#define S_PER  8
#define WARM   16

// ws layout (floats): base 315,584 f = 1,262,336 B; optional pre-split B adds
// 2 x 327,680 ushorts = 1,310,720 B  ->  total 2,573,056 B (gated on ws_size).
#define WS_BASE_FLOATS 315584
#define WS_NEED_BSP    2573056

typedef __attribute__((ext_vector_type(8))) short bfrag;   // 8 bf16 (4 VGPR)
typedef __attribute__((ext_vector_type(4))) float ffrag;   // 4 fp32 acc
typedef __attribute__((ext_vector_type(4))) float fvec4;

__device__ __forceinline__ float softplus_f(float x) {
    return log1pf(expf(-fabsf(x))) + fmaxf(x, 0.f);
}

__device__ __forceinline__ unsigned short bf_hi(float f) {  // RNE fp32->bf16
    unsigned u = __float_as_uint(f);
    u = u + 0x7FFFu + ((u >> 16) & 1u);
    return (unsigned short)(u >> 16);
}

__device__ __forceinline__ float elu_f(float x) {
    return (x > 0.f) ? x : (__builtin_amdgcn_exp2f(x * L2E) - 1.f);
}

// cross-half (lane i <-> lane i+32) sum without LDS: v_permlane32_swap is a
// VALU op (~8 cy) vs ds_bpermute (~120 cy exposed at low occupancy).
__device__ __forceinline__ float half_sum(float x) {
#if __has_builtin(__builtin_amdgcn_permlane32_swap)
    auto r = __builtin_amdgcn_permlane32_swap(__float_as_int(x), __float_as_int(x),
                                              false, false);
    return __int_as_float(r[0]) + __int_as_float(r[1]);
#else
    int pidx = ((threadIdx.x & 63) ^ 32) * 4;
    return x + __int_as_float(
        __builtin_amdgcn_ds_bpermute(pidx, __float_as_int(x)));
#endif
}

// ---------------------------------------------------------------------------
// K0C v2: combined param precompute + fc1_w pre-split (read-coalesced:
// linear fc1_w read -> inverse-permuted 2B scatter writes; pads zeroed).
// Blocks 0..511: splitB. Block 512: param precompute.
// ---------------------------------------------------------------------------
__global__ __launch_bounds__(640) void k0_combined(
    const float* __restrict__ sw, const float* __restrict__ smu,
    const float* __restrict__ ssig, const float* __restrict__ serev,
    const float* __restrict__ smask,
    const float* __restrict__ w, const float* __restrict__ mu,
    const float* __restrict__ sigma, const float* __restrict__ erev,
    const float* __restrict__ mask,
    const float* __restrict__ gleak, const float* __restrict__ vleak,
    const float* __restrict__ cm,
    float* __restrict__ sc1, float* __restrict__ sc0,
    float* __restrict__ swe, float* __restrict__ swp,
    float* __restrict__ rc1, float* __restrict__ rc0,
    float* __restrict__ rwe, float* __restrict__ rwp,
    float* __restrict__ neu,
    const float* __restrict__ fc1_w,
    unsigned short* __restrict__ bhi, unsigned short* __restrict__ blo,
    int use_bsp)
{
    if (blockIdx.x == 512) {
        int t = threadIdx.x;
        if (t < 608) {   // sensory (32 x 19)
            float sp = softplus_f(sw[t]);
            float c1 = ssig[t] * L2E;
            sc1[t] = c1;
            sc0[t] = c1 * smu[t];
            swe[t] = sp * serev[t];
            swp[t] = sp * smask[t];
        }
        if (t < 361) {   // recurrent (19 x 19), layout [src*19 + tgt]
            float wp = softplus_f(w[t]) * mask[t];
            float c1 = sigma[t] * L2E;
            rc1[t] = c1;
            rc0[t] = c1 * mu[t];
            rwe[t] = wp * erev[t];
            rwp[t] = wp;
        }
        if (t < 64) {
            if (t < 19) {
                float g   = softplus_f(gleak[t]);
                float cmt = softplus_f(cm[t]) * 6.f;   // ODE_UNFOLDS
                neu[t]       = cmt;
                neu[64 + t]  = g * vleak[t];
                neu[128 + t] = cmt + g + EPS_LTC;
            } else {
                neu[t] = 0.f; neu[64 + t] = 0.f; neu[128 + t] = 1.f;
            }
        }
        return;
    }
    if (!use_bsp) return;
    int i = blockIdx.x * 640 + threadIdx.x;   // 0 .. 327,679
    int n, o, r;
    float v;
    if (i < 326656) {                 // real element: coalesced linear read
        n = i / 5104;                 // 64 rows of KTOT=5104
        int k = i - n * 5104;
        o = k / 638;                  // channel-chunk within row
        r = k - o * 638;
        v = fc1_w[i];
    } else {                          // pad slots (r=638,639) -> zero
        int p = i - 326656;           // 0..1023 = 64 n x 8 o x 2 r
        n = p >> 4;
        int rem = p & 15;
        o = rem >> 1;
        r = 638 + (rem & 1);
        v = 0.f;
    }
    // inverse of the fragment-interleaved mapping used by k12's LOADB.
    int kc = r >> 2, q = o >> 1;
    int j  = (o & 1) * 4 + (r & 3);
    int g  = (((kc * 16 + q * 4 + (n >> 4)) * 16) + (n & 15)) * 8 + j;
    unsigned short h = bf_hi(v);
    bhi[g] = h;
    blo[g] = bf_hi(v - __uint_as_float((unsigned)h << 16));
}

// ---------------------------------------------------------------------------
// K12 v17: INTERLEAVED K-split + global x (no x LDS tile).
//  v16 (75-81 us): MfmaUtil 8%, VALUBusy 40%, occupancy 20% -- per-wave
//  ~80% stall at 2 waves/SIMD, forced ONLY by the 132 KB x-tile (VGPR=120
//  would allow 4/SIMD). R0's global-x thrash (435 MB) was caused by the
//  BLOCKED K-split: 8 waves at 8 different conv-row regions -> per-XCD live
//  window 3-6 MB > 4 MB L2. Fix: kc = wv + 8*i (interleaved) keeps all 8
//  waves spatially adjacent -> per-block live x-window ~17-34 KB (L1-class),
//  per-XCD ~1-2 MB << L2. Drop the x tile: LDS 132->47.6 KB -> 2 blocks/CU
//  = 4 waves/SIMD; grid fits one dispatch round. Conv code identical to
//  v10's global-window path (numerically proven); accumulation order per
//  wave changes but the 8-partial epilogue reduction is order-agnostic.
//  KILL-SWITCH: if FETCH >> 200 MB (wave-drift thrash), revert to v16.
// ---------------------------------------------------------------------------
#define LOADWIN(KC, WB) do {                                                  \
    int r0_  = (KC) * 4;                                                      \
    int oh0_ = (r0_ * 565) >> 14;                                             \
    int ow0_ = r0_ - oh0_ * 29;                                               \
    _Pragma("unroll")                                                         \
    for (int cc_ = 0; cc_ < 3; cc_++) {                                       \
        const float* a0_ = xls + cc_ * 690 + oh0_ * 30 + ow0_;                \
        fvec4 v0_, v1_;                                                       \
        __builtin_memcpy(&v0_, a0_, 16);                                      \
        __builtin_memcpy(&v1_, a0_ + 30, 16);                                 \
        WB[cc_*10+0]=v0_.x; WB[cc_*10+1]=v0_.y; WB[cc_*10+2]=v0_.z;           \
        WB[cc_*10+3]=v0_.w; WB[cc_*10+4]=a0_[4];                              \
        WB[cc_*10+5]=v1_.x; WB[cc_*10+6]=v1_.y; WB[cc_*10+7]=v1_.z;           \
        WB[cc_*10+8]=v1_.w; WB[cc_*10+9]=a0_[34];                             \
    }                                                                         \
} while (0)

#define PACKA(Y0, Y1, AH, AL) do {                                            \
    _Pragma("unroll")                                                         \
    for (int j_ = 0; j_ < 4; j_++) {                                          \
        unsigned short h0_ = bf_hi(Y0[j_]);                                   \
        AH[j_] = (short)h0_;                                                  \
        AL[j_] = (short)bf_hi(Y0[j_] - __uint_as_float((unsigned)h0_ << 16)); \
        unsigned short h1_ = bf_hi(Y1[j_]);                                   \
        AH[4+j_] = (short)h1_;                                                \
        AL[4+j_] = (short)bf_hi(Y1[j_] - __uint_as_float((unsigned)h1_ << 16));\
    }                                                                         \
} while (0)

#define BUILDA_FAST(WB, AH, AL) do {                                          \
    float y0_[4], y1_[4];                                                     \
    _Pragma("unroll")                                                         \
    for (int rr_ = 0; rr_ < 4; rr_++) {                                       \
        float a0v_ = cb0, a1v_ = cb1;                                         \
        _Pragma("unroll")                                                     \
        for (int cc_ = 0; cc_ < 3; cc_++) {                                   \
            float x00_ = WB[cc_*10+rr_],   x01_ = WB[cc_*10+rr_+1];           \
            float x10_ = WB[cc_*10+5+rr_], x11_ = WB[cc_*10+6+rr_];           \
            a0v_ = fmaf(x00_, cw0[cc_*4+0], a0v_);                            \
            a0v_ = fmaf(x01_, cw0[cc_*4+1], a0v_);                            \
            a0v_ = fmaf(x10_, cw0[cc_*4+2], a0v_);                            \
            a0v_ = fmaf(x11_, cw0[cc_*4+3], a0v_);                            \
            a1v_ = fmaf(x00_, cw1[cc_*4+0], a1v_);                            \
            a1v_ = fmaf(x01_, cw1[cc_*4+1], a1v_);                            \
            a1v_ = fmaf(x10_, cw1[cc_*4+2], a1v_);                            \
            a1v_ = fmaf(x11_, cw1[cc_*4+3], a1v_);                            \
        }                                                                     \
        y0_[rr_] = elu_f(a0v_);                                               \
        y1_[rr_] = elu_f(a1v_);                                               \
    }                                                                         \
    PACKA(y0_, y1_, AH, AL);                                                  \
} while (0)

#define BUILDA_SLOW(KC, AH, AL) do {                                          \
    float y0_[4], y1_[4];                                                     \
    int r0_ = (KC) * 4;                                                       \
    _Pragma("unroll")                                                         \
    for (int rr_ = 0; rr_ < 4; rr_++) {                                       \
        int r_ = r0_ + rr_;                                                   \
        if (r_ < 638) {                                                       \
            int oh_ = (r_ * 565) >> 14;                                       \
            const float* xp_ = xls + oh_ * 30 + (r_ - oh_ * 29);              \
            float a0v_ = cb0, a1v_ = cb1;                                     \
            _Pragma("unroll")                                                 \
            for (int cc_ = 0; cc_ < 3; cc_++) {                               \
                float x00_ = xp_[cc_*690],    x01_ = xp_[cc_*690+1];          \
                float x10_ = xp_[cc_*690+30], x11_ = xp_[cc_*690+31];         \
                a0v_ = fmaf(x00_, cw0[cc_*4+0], a0v_);                        \
                a0v_ = fmaf(x01_, cw0[cc_*4+1], a0v_);                        \
                a0v_ = fmaf(x10_, cw0[cc_*4+2], a0v_);                        \
                a0v_ = fmaf(x11_, cw0[cc_*4+3], a0v_);                        \
                a1v_ = fmaf(x00_, cw1[cc_*4+0], a1v_);                        \
                a1v_ = fmaf(x01_, cw1[cc_*4+1], a1v_);                        \
                a1v_ = fmaf(x10_, cw1[cc_*4+2], a1v_);                        \
                a1v_ = fmaf(x11_, cw1[cc_*4+3], a1v_);                        \
            }                                                                 \
            y0_[rr_] = elu_f(a0v_);                                           \
            y1_[rr_] = elu_f(a1v_);                                           \
        } else { y0_[rr_] = 0.f; y1_[rr_] = 0.f; }                            \
    }                                                                         \
    PACKA(y0_, y1_, AH, AL);                                                  \
} while (0)

#define LOADB(KC, BH, BL) do {                                                \
    _Pragma("unroll")                                                         \
    for (int nt_ = 0; nt_ < 4; nt_++) {                                       \
        size_t off_ = ((size_t)((KC) * 16 + q * 4 + nt_) * 16 + mn) * 8;      \
        BH[nt_] = *(const bfrag*)(bhi + off_);                                \
        BL[nt_] = *(const bfrag*)(blo + off_);                                \
    }                                                                         \
} while (0)

#define MFMA3(AH, AL, BH, BL) do {                                            \
    _Pragma("unroll")                                                         \
    for (int nt_ = 0; nt_ < 4; nt_++) {                                       \
        acc[nt_] = __builtin_amdgcn_mfma_f32_16x16x32_bf16(AH, BH[nt_], acc[nt_], 0, 0, 0); \
        acc[nt_] = __builtin_amdgcn_mfma_f32_16x16x32_bf16(AH, BL[nt_], acc[nt_], 0, 0, 0); \
        acc[nt_] = __builtin_amdgcn_mfma_f32_16x16x32_bf16(AL, BH[nt_], acc[nt_], 0, 0, 0); \
    }                                                                         \
} while (0)

__global__ __launch_bounds__(512, 1) void k12_frontend(
    const float* __restrict__ x, const float* __restrict__ conv_w,
    const float* __restrict__ conv_b,
    const float* __restrict__ fc1_w, const float* __restrict__ fc1_b,
    const float* __restrict__ fc2_w, const float* __restrict__ fc2_b,
    const float* __restrict__ iw, const float* __restrict__ ib,
    const float* __restrict__ sc1, const float* __restrict__ sc0,
    const float* __restrict__ swe, const float* __restrict__ swp,
    const unsigned short* __restrict__ bhi,
    const unsigned short* __restrict__ blo, int use_bsp,
    float* __restrict__ wn_s, float* __restrict__ wd_s)
{
    // Epilogue-only LDS: 11,920 f = 47.7 KB -> 2 blocks/CU (VGPR ~120 ->
    // 4 waves/SIMD).
    __shared__ __align__(16) float smem[11920];
    float* redS = smem;            // [8][16][64] = 8192 f partial-C buffer
    float* hS   = smem + 8192;     // 16 x 68 = 1088 f
    float* w2S  = smem + 9312;     // [s][n] stride 65, 2080 f
    float* seqS = smem + 11392;    // [sample][s] stride 33, 528 f

    const int t    = threadIdx.x;   // 0..511
    const int b0   = blockIdx.x * 16;
    const int lane = t & 63;
    const int wv   = t >> 6;        // wave 0..7 -> INTERLEAVED kc residue
    const int q    = lane >> 4;     // quad -> channel pair 2q,2q+1
    const int mn   = lane & 15;     // sample (A) / out-within-tile (B)
    const int o0   = 2 * q;

    // conv weights + bias for this lane's channel pair, in registers
    float cw0[12], cw1[12];
    #pragma unroll
    for (int i = 0; i < 12; i++) {
        cw0[i] = conv_w[o0 * 12 + i];
        cw1[i] = conv_w[o0 * 12 + 12 + i];
    }
    const float cb0 = conv_b[o0], cb1 = conv_b[o0 + 1];
    // this lane's sample, directly in GLOBAL (interleaved kc keeps the
    // block's live window L1/L2-resident)
    const float* xls = x + (size_t)(b0 + mn) * 2070;

    ffrag acc[4];
    #pragma unroll
    for (int nt = 0; nt < 4; nt++) acc[nt] = (ffrag){0.f, 0.f, 0.f, 0.f};

    // fast-path predicate: all 4 positions of chunk kc in one conv row
    auto isFast = [](int kc) {
        int r0 = kc * 4;
        int oh0 = (r0 * 565) >> 14;
        int ow0 = r0 - oh0 * 29;
        return (ow0 <= 25 && r0 + 3 <= 637);
    };

    if (use_bsp) {
        float winA[30], winB[30];
        bfrag bh0[4], bl0[4], bh1[4], bl1[4];
        bool fA = isFast(wv);
        if (fA) LOADWIN(wv, winA);
        LOADB(wv, bh0, bl0);
        for (int i = 0; i < 20; i += 2) {
            const int kcA = wv + 8 * i;       // this wave's kc stream: wv+8k
            const int kcB = kcA + 8;
            // -- half 1: compute kcA from winA/b0; prefetch kcB -> winB/b1 --
            bool fB = isFast(kcB);
            LOADB(kcB, bh1, bl1);
            if (fB) LOADWIN(kcB, winB);
            {
                bfrag a_hi, a_lo;
                if (fA) { BUILDA_FAST(winA, a_hi, a_lo); }
                else    { BUILDA_SLOW(kcA, a_hi, a_lo); }
                MFMA3(a_hi, a_lo, bh0, bl0);
            }
            // -- half 2: compute kcB from winB/b1; prefetch kcA+16 --
            fA = (i + 2 < 20) && isFast(kcA + 16);
            if (i + 2 < 20) {
                LOADB(kcA + 16, bh0, bl0);
                if (fA) LOADWIN(kcA + 16, winA);
            }
            {
                bfrag a_hi, a_lo;
                if (fB) { BUILDA_FAST(winB, a_hi, a_lo); }
                else    { BUILDA_SLOW(kcB, a_hi, a_lo); }
                MFMA3(a_hi, a_lo, bh1, bl1);
            }
        }
    } else {
        // fallback: in-loop fp32 load + split (ws too small for pre-split B)
        for (int i = 0; i < 20; i++) {
            const int kc = wv + 8 * i;
            bfrag a_hi, a_lo;
            BUILDA_SLOW(kc, a_hi, a_lo);
            #pragma unroll
            for (int nt = 0; nt < 4; nt++) {
                int n = nt * 16 + mn;
                bfrag b_h, b_l;
                #pragma unroll
                for (int j = 0; j < 8; j++) {
                    int o = o0 + (j >> 2);
                    int r = kc * 4 + (j & 3);
                    float vv = (r < 638) ? fc1_w[(size_t)n * KTOT + o * 638 + r] : 0.f;
                    unsigned short h = bf_hi(vv);
                    b_h[j] = (short)h;
                    b_l[j] = (short)bf_hi(vv - __uint_as_float((unsigned)h << 16));
                }
                acc[nt] = __builtin_amdgcn_mfma_f32_16x16x32_bf16(a_hi, b_h, acc[nt], 0, 0, 0);
                acc[nt] = __builtin_amdgcn_mfma_f32_16x16x32_bf16(a_hi, b_l, acc[nt], 0, 0, 0);
                acc[nt] = __builtin_amdgcn_mfma_f32_16x16x32_bf16(a_lo, b_h, acc[nt], 0, 0, 0);
            }
        }
    }

    // ---- cross-wave K reduction: 8 partials -> LDS -> sum + bias + ReLU ----
    // C/D layout: col = lane&15 -> n-within-tile, row = q*4 + reg -> m.
    #pragma unroll
    for (int nt = 0; nt < 4; nt++) {
        int n = nt * 16 + mn;
        #pragma unroll
        for (int rg = 0; rg < 4; rg++) {
            int m = q * 4 + rg;
            redS[(wv * 16 + m) * 64 + n] = acc[nt][rg];
        }
    }
    __syncthreads();
    #pragma unroll
    for (int e = 0; e < 2; e++) {
        int flat = e * 512 + t;           // 1024 = 16*64
        int m = flat >> 6, n = flat & 63;
        float s = 0.f;
        #pragma unroll
        for (int p = 0; p < 8; p++) s += redS[(p * 16 + m) * 64 + n];
        hS[m * 68 + n] = fmaxf(s + fc1_b[n], 0.f);
    }
    // ---- stage fc2 weights ----
    #pragma unroll
    for (int e = 0; e < 4; e++) {
        int flat = e * 512 + t;           // 2048 = 32*64
        int s = flat >> 6, n = flat & 63;
        w2S[s * 65 + n] = fc2_w[flat];
    }
    __syncthreads();

    // ---- fc2 + input affine -> seq (16 samples x 32 sensory = 512 items) ----
    {
        int s = t & 31, bl = t >> 5;
        float a2 = fc2_b[s];
        #pragma unroll 8
        for (int n = 0; n < 64; n++)
            a2 = fmaf(hS[bl * 68 + n], w2S[s * 65 + n], a2);
        seqS[bl * 33 + s] = a2 * iw[s] + ib[s];
    }
    __syncthreads();

    // ---- sensory synapse sums (16 samples x 19 neurons = 304 items) ----
    if (t < 304) {
        int n = t % 19, bl = t / 19;
        float wn = 0.f, wd = 0.f;
        #pragma unroll
        for (int s = 0; s < 32; s++) {
            float xx = sc0[s * 19 + n] - sc1[s * 19 + n] * seqS[bl * 33 + s];
            float ee = __builtin_amdgcn_exp2f(xx);
            float uu = __builtin_amdgcn_rcpf(1.f + ee);
            wn = fmaf(swe[s * 19 + n], uu, wn);
            wd = fmaf(swp[s * 19 + n], uu, wd);
        }
        wn_s[(b0 + bl) * 19 + n] = wn;
        wd_s[(b0 + bl) * 19 + n] = wd;
    }
}

// ---------------------------------------------------------------------------
// K3P v4 (REVERTED to measured-best: batched bpermute, p-split 10
// sigmoids/lane, permlane half_sum, tree sums, 1024x8). Scan experiments
// closed out: batching was the one win (88->~74); TLP (2048x4: 77),
// readlane-19 (90), readlane-pair (82.7) all null/worse -> dep-chain +
// trans-issue bound; ~74 us is this structure's floor.
// ---------------------------------------------------------------------------
__global__ __launch_bounds__(64, 1) void k3p2_scan(
    const float* __restrict__ wn_s, const float* __restrict__ wd_s,
    const float* __restrict__ rc1, const float* __restrict__ rc0,
    const float* __restrict__ rwe, const float* __restrict__ rwp,
    const float* __restrict__ neu,
    const float* __restrict__ out_w, const float* __restrict__ out_b,
    float* __restrict__ out)
{
    const int l    = threadIdx.x;       // 0..63
    const int col  = l & 31;            // target neuron (19 real + 13 pad)
    const int p    = l >> 5;            // source half
    const int cidx = (col < 19) ? col : 0;

    float ca[10], cb[10], cwe[10], cwp[10];
    int gidx[10];
    #pragma unroll
    for (int j = 0; j < 10; j++) {
        int s = p * 10 + j;
        bool e = (col < 19) && (s < 19);
        int idx = e ? (s * 19 + col) : 0;
        ca[j]  = e ? rc1[idx] : 0.f;
        cb[j]  = e ? rc0[idx] : 0.f;
        cwe[j] = e ? rwe[idx] : 0.f;
        cwp[j] = e ? rwp[idx] : 0.f;
        gidx[j] = ((s < 19) ? s : 0) * 4;
    }

    const float cmt  = neu[cidx];
    const float gvl  = neu[64 + cidx];
    const float den0 = neu[128 + cidx];
    const float owv  = out_w[0];
    const float obv  = out_b[0];

    const int c       = blockIdx.x;
    const int s_out   = c * S_PER;
    const int s_begin = (s_out > WARM) ? (s_out - WARM) : 0;
    const int s_end   = s_out + S_PER;

    float v = 0.f;
    float wnc = wn_s[s_begin * 19 + cidx];
    float wdc = wd_s[s_begin * 19 + cidx];

    for (int tt = s_begin; tt < s_end; tt++) {
        int nt = (tt + 1 < T_STEPS) ? (tt + 1) : (T_STEPS - 1);
        float wnn = wn_s[nt * 19 + cidx];
        float wdn = wd_s[nt * 19 + cidx];

        #pragma unroll
        for (int u = 0; u < 6; u++) {
            // ---- batched gather: issue all 10 bpermutes, then compute ----
            float vs[10];
            #pragma unroll
            for (int j = 0; j < 10; j++)
                vs[j] = __int_as_float(
                    __builtin_amdgcn_ds_bpermute(gidx[j], __float_as_int(v)));

            float tn[10], td[10];
            #pragma unroll
            for (int j = 0; j < 10; j++) {
                float xx = fmaf(-ca[j], vs[j], cb[j]);
                float ee = __builtin_amdgcn_exp2f(xx);
                float uu = __builtin_amdgcn_rcpf(1.f + ee);
                tn[j] = cwe[j] * uu;
                td[j] = cwp[j] * uu;
            }
            // tree sums (order change vs serial chain is within tolerance)
            float pn = (((tn[0] + tn[1]) + (tn[2] + tn[3]))
                      + ((tn[4] + tn[5]) + (tn[6] + tn[7])))
                      + (tn[8] + tn[9]);
            float pd = (((td[0] + td[1]) + (td[2] + td[3]))
                      + ((td[4] + td[5]) + (td[6] + td[7])))
                      + (td[8] + td[9]);

            // cross-half reduce, VALU-only
            pn = half_sum(pn);
            pd = half_sum(pd);

            float num = fmaf(cmt, v, gvl) + (pn + wnc);
            float den = den0 + pd + wdc;
            v = num * __builtin_amdgcn_rcpf(den);
        }
        if (l == 0 && tt >= s_out) out[tt] = fmaf(v, owv, obv);
        wnc = wnn; wdc = wdn;
    }
}

// ---------------------------------------------------------------------------
extern "C" void kernel_launch(void* const* d_in, const int* in_sizes, int n_in,
                              void* d_out, int out_size, void* d_ws, size_t ws_size,
                              hipStream_t stream) {
    const float* x      = (const float*)d_in[0];
    const float* conv_w = (const float*)d_in[1];
    const float* conv_b = (const float*)d_in[2];
    const float* fc1_w  = (const float*)d_in[3];
    const float* fc1_b  = (const float*)d_in[4];
    const float* fc2_w  = (const float*)d_in[5];
    const float* fc2_b  = (const float*)d_in[6];
    const float* iw     = (const float*)d_in[7];
    const float* ib     = (const float*)d_in[8];
    const float* sw     = (const float*)d_in[9];
    const float* smu    = (const float*)d_in[10];
    const float* ssig   = (const float*)d_in[11];
    const float* serev  = (const float*)d_in[12];
    const float* smask  = (const float*)d_in[13];
    const float* w      = (const float*)d_in[14];
    const float* mu     = (const float*)d_in[15];
    const float* sigma  = (const float*)d_in[16];
    const float* erev   = (const float*)d_in[17];
    const float* mask   = (const float*)d_in[18];
    const float* gleak  = (const float*)d_in[19];
    const float* vleak  = (const float*)d_in[20];
    const float* cm     = (const float*)d_in[21];
    const float* ow     = (const float*)d_in[22];
    const float* ob     = (const float*)d_in[23];

    float* ws   = (float*)d_ws;
    float* wn_s = ws;                    // 8192*19 = 155648
    float* wd_s = wn_s + 155648;         // 155648
    float* sc1  = wd_s + 155648;         // 640 each
    float* sc0  = sc1 + 640;
    float* swe  = sc0 + 640;
    float* swp  = swe + 640;
    float* rc1  = swp + 640;             // 384 each
    float* rc0  = rc1 + 384;
    float* rwe  = rc0 + 384;
    float* rwp  = rwe + 384;
    float* neu  = rwp + 384;             // 192  (base ends at 315,584 floats)
    const int use_bsp = (ws_size >= (size_t)WS_NEED_BSP) ? 1 : 0;
    unsigned short* bhi = (unsigned short*)(ws + WS_BASE_FLOATS);
    unsigned short* blo = bhi + 64 * KP;
    (void)in_sizes; (void)n_in; (void)out_size;

    hipLaunchKernelGGL(k0_combined, dim3(513), dim3(640), 0, stream,
        sw, smu, ssig, serev, smask, w, mu, sigma, erev, mask,
        gleak, vleak, cm, sc1, sc0, swe, swp, rc1, rc0, rwe, rwp, neu,
        fc1_w, bhi, blo, use_bsp);

    hipLaunchKernelGGL(k12_frontend, dim3(512), dim3(512), 0, stream,
        x, conv_w, conv_b, fc1_w, fc1_b, fc2_w, fc2_b, iw, ib,
        sc1, sc0, swe, swp, bhi, blo, use_bsp, wn_s, wd_s);

    hipLaunchKernelGGL(k3p2_scan, dim3(SCAN_CHUNKS), dim3(64), 0, stream,
        wn_s, wd_s, rc1, rc0, rwe, rwp, neu, ow, ob, (float*)d_out);
}

// Round 13
// 253.117 us; speedup vs baseline: 1.2743x; 1.2743x over previous
//
#include <hip/hip_runtime.h>
#include <hip/hip_bf16.h>
#include <math.h>

#define L2E 1.4426950408889634f
#define T_STEPS 8192
#define KTOT 5104   // 8 channels * 638 spatial (22*29)
#define EPS_LTC 1e-8f
#define KP 5120     // permuted/padded K (160 chunks x 32)

// scan chunking: 1024 chunks x 8 steps, 16-step burn-in (chunks 0,1 exact).
#define SCAN_CHUNKS 1024
#define S_PER  8
#define WARM   16

// ws layout (floats): base 315,584 f = 1,262,336 B; optional pre-split B adds
// 2 x 327,680 ushorts = 1,310,720 B  ->  total 2,573,056 B (gated on ws_size).
#define WS_BASE_FLOATS 315584
#define WS_NEED_BSP    2573056

typedef __attribute__((ext_vector_type(8))) short bfrag;   // 8 bf16 (4 VGPR)
typedef __attribute__((ext_vector_type(4))) float ffrag;   // 4 fp32 acc
typedef __attribute__((ext_vector_type(4))) float fvec4;

__device__ __forceinline__ float softplus_f(float x) {
    return log1pf(expf(-fabsf(x))) + fmaxf(x, 0.f);
}

__device__ __forceinline__ unsigned short bf_hi(float f) {  // RNE fp32->bf16
    unsigned u = __float_as_uint(f);
    u = u + 0x7FFFu + ((u >> 16) & 1u);
    return (unsigned short)(u >> 16);
}

__device__ __forceinline__ float elu_f(float x) {
    return (x > 0.f) ? x : (__builtin_amdgcn_exp2f(x * L2E) - 1.f);
}

// cross-half (lane i <-> lane i+32) sum without LDS: v_permlane32_swap is a
// VALU op (~8 cy) vs ds_bpermute (~120 cy exposed at low occupancy).
__device__ __forceinline__ float half_sum(float x) {
#if __has_builtin(__builtin_amdgcn_permlane32_swap)
    auto r = __builtin_amdgcn_permlane32_swap(__float_as_int(x), __float_as_int(x),
                                              false, false);
    return __int_as_float(r[0]) + __int_as_float(r[1]);
#else
    int pidx = ((threadIdx.x & 63) ^ 32) * 4;
    return x + __int_as_float(
        __builtin_amdgcn_ds_bpermute(pidx, __float_as_int(x)));
#endif
}

// ---------------------------------------------------------------------------
// K0C: combined param precompute + fc1_w pre-split (one launch instead of
// two). Blocks 0..511: splitB (gather form — R7-proven). Block 512: params.
// ---------------------------------------------------------------------------
__global__ __launch_bounds__(640) void k0_combined(
    const float* __restrict__ sw, const float* __restrict__ smu,
    const float* __restrict__ ssig, const float* __restrict__ serev,
    const float* __restrict__ smask,
    const float* __restrict__ w, const float* __restrict__ mu,
    const float* __restrict__ sigma, const float* __restrict__ erev,
    const float* __restrict__ mask,
    const float* __restrict__ gleak, const float* __restrict__ vleak,
    const float* __restrict__ cm,
    float* __restrict__ sc1, float* __restrict__ sc0,
    float* __restrict__ swe, float* __restrict__ swp,
    float* __restrict__ rc1, float* __restrict__ rc0,
    float* __restrict__ rwe, float* __restrict__ rwp,
    float* __restrict__ neu,
    const float* __restrict__ fc1_w,
    unsigned short* __restrict__ bhi, unsigned short* __restrict__ blo,
    int use_bsp)
{
    if (blockIdx.x == 512) {
        int t = threadIdx.x;
        if (t < 608) {   // sensory (32 x 19)
            float sp = softplus_f(sw[t]);
            float c1 = ssig[t] * L2E;
            sc1[t] = c1;
            sc0[t] = c1 * smu[t];
            swe[t] = sp * serev[t];
            swp[t] = sp * smask[t];
        }
        if (t < 361) {   // recurrent (19 x 19), layout [src*19 + tgt]
            float wp = softplus_f(w[t]) * mask[t];
            float c1 = sigma[t] * L2E;
            rc1[t] = c1;
            rc0[t] = c1 * mu[t];
            rwe[t] = wp * erev[t];
            rwp[t] = wp;
        }
        if (t < 64) {
            if (t < 19) {
                float g   = softplus_f(gleak[t]);
                float cmt = softplus_f(cm[t]) * 6.f;   // ODE_UNFOLDS
                neu[t]       = cmt;
                neu[64 + t]  = g * vleak[t];
                neu[128 + t] = cmt + g + EPS_LTC;
            } else {
                neu[t] = 0.f; neu[64 + t] = 0.f; neu[128 + t] = 1.f;
            }
        }
        return;
    }
    if (!use_bsp) return;
    // splitB: fragment-interleaved bf16 hi/lo of fc1_w.
    int g = blockIdx.x * 640 + threadIdx.x;   // 0 .. 64*KP-1
    int j  = g & 7;
    int mn = (g >> 3) & 15;
    int nt = (g >> 7) & 3;
    int q  = (g >> 9) & 3;
    int kc = g >> 11;
    int n  = nt * 16 + mn;
    int o  = 2 * q + (j >> 2);
    int r  = kc * 4 + (j & 3);
    float v = (r < 638) ? fc1_w[n * KTOT + o * 638 + r] : 0.f;
    unsigned short h = bf_hi(v);
    bhi[g] = h;
    blo[g] = bf_hi(v - __uint_as_float((unsigned)h << 16));
}

// ---------------------------------------------------------------------------
// K12 v16 (REVERTED to R7-proven state: 75-82 us, VGPR 120, no spill).
//  v17 post-mortem: dropping the x LDS tile did NOT raise occupancy (21%,
//  VGPR rose to 128, minor spill returned) and exposed L2 latency (~200 cy)
//  under the shallow pipeline -> 141 us. The LDS x-tile at 1 block/CU is
//  load-bearing: it makes per-kc memory latency cheap for the 2-wave/SIMD
//  schedule. Macro-ized 2-deep pipelined K-loop; pre-split B.
// ---------------------------------------------------------------------------
#define LOADWIN(KC, WB) do {                                                  \
    int r0_  = (KC) * 4;                                                      \
    int oh0_ = (r0_ * 565) >> 14;                                             \
    int ow0_ = r0_ - oh0_ * 29;                                               \
    _Pragma("unroll")                                                         \
    for (int cc_ = 0; cc_ < 3; cc_++) {                                       \
        const float* a0_ = xls + cc_ * 690 + oh0_ * 30 + ow0_;                \
        fvec4 v0_, v1_;                                                       \
        __builtin_memcpy(&v0_, a0_, 16);                                      \
        __builtin_memcpy(&v1_, a0_ + 30, 16);                                 \
        WB[cc_*10+0]=v0_.x; WB[cc_*10+1]=v0_.y; WB[cc_*10+2]=v0_.z;           \
        WB[cc_*10+3]=v0_.w; WB[cc_*10+4]=a0_[4];                              \
        WB[cc_*10+5]=v1_.x; WB[cc_*10+6]=v1_.y; WB[cc_*10+7]=v1_.z;           \
        WB[cc_*10+8]=v1_.w; WB[cc_*10+9]=a0_[34];                             \
    }                                                                         \
} while (0)

#define PACKA(Y0, Y1, AH, AL) do {                                            \
    _Pragma("unroll")                                                         \
    for (int j_ = 0; j_ < 4; j_++) {                                          \
        unsigned short h0_ = bf_hi(Y0[j_]);                                   \
        AH[j_] = (short)h0_;                                                  \
        AL[j_] = (short)bf_hi(Y0[j_] - __uint_as_float((unsigned)h0_ << 16)); \
        unsigned short h1_ = bf_hi(Y1[j_]);                                   \
        AH[4+j_] = (short)h1_;                                                \
        AL[4+j_] = (short)bf_hi(Y1[j_] - __uint_as_float((unsigned)h1_ << 16));\
    }                                                                         \
} while (0)

#define BUILDA_FAST(WB, AH, AL) do {                                          \
    float y0_[4], y1_[4];                                                     \
    _Pragma("unroll")                                                         \
    for (int rr_ = 0; rr_ < 4; rr_++) {                                       \
        float a0v_ = cb0, a1v_ = cb1;                                         \
        _Pragma("unroll")                                                     \
        for (int cc_ = 0; cc_ < 3; cc_++) {                                   \
            float x00_ = WB[cc_*10+rr_],   x01_ = WB[cc_*10+rr_+1];           \
            float x10_ = WB[cc_*10+5+rr_], x11_ = WB[cc_*10+6+rr_];           \
            a0v_ = fmaf(x00_, cw0[cc_*4+0], a0v_);                            \
            a0v_ = fmaf(x01_, cw0[cc_*4+1], a0v_);                            \
            a0v_ = fmaf(x10_, cw0[cc_*4+2], a0v_);                            \
            a0v_ = fmaf(x11_, cw0[cc_*4+3], a0v_);                            \
            a1v_ = fmaf(x00_, cw1[cc_*4+0], a1v_);                            \
            a1v_ = fmaf(x01_, cw1[cc_*4+1], a1v_);                            \
            a1v_ = fmaf(x10_, cw1[cc_*4+2], a1v_);                            \
            a1v_ = fmaf(x11_, cw1[cc_*4+3], a1v_);                            \
        }                                                                     \
        y0_[rr_] = elu_f(a0v_);                                               \
        y1_[rr_] = elu_f(a1v_);                                               \
    }                                                                         \
    PACKA(y0_, y1_, AH, AL);                                                  \
} while (0)

#define BUILDA_SLOW(KC, AH, AL) do {                                          \
    float y0_[4], y1_[4];                                                     \
    int r0_ = (KC) * 4;                                                       \
    _Pragma("unroll")                                                         \
    for (int rr_ = 0; rr_ < 4; rr_++) {                                       \
        int r_ = r0_ + rr_;                                                   \
        if (r_ < 638) {                                                       \
            int oh_ = (r_ * 565) >> 14;                                       \
            const float* xp_ = xls + oh_ * 30 + (r_ - oh_ * 29);              \
            float a0v_ = cb0, a1v_ = cb1;                                     \
            _Pragma("unroll")                                                 \
            for (int cc_ = 0; cc_ < 3; cc_++) {                               \
                float x00_ = xp_[cc_*690],    x01_ = xp_[cc_*690+1];          \
                float x10_ = xp_[cc_*690+30], x11_ = xp_[cc_*690+31];         \
                a0v_ = fmaf(x00_, cw0[cc_*4+0], a0v_);                        \
                a0v_ = fmaf(x01_, cw0[cc_*4+1], a0v_);                        \
                a0v_ = fmaf(x10_, cw0[cc_*4+2], a0v_);                        \
                a0v_ = fmaf(x11_, cw0[cc_*4+3], a0v_);                        \
                a1v_ = fmaf(x00_, cw1[cc_*4+0], a1v_);                        \
                a1v_ = fmaf(x01_, cw1[cc_*4+1], a1v_);                        \
                a1v_ = fmaf(x10_, cw1[cc_*4+2], a1v_);                        \
                a1v_ = fmaf(x11_, cw1[cc_*4+3], a1v_);                        \
            }                                                                 \
            y0_[rr_] = elu_f(a0v_);                                           \
            y1_[rr_] = elu_f(a1v_);                                           \
        } else { y0_[rr_] = 0.f; y1_[rr_] = 0.f; }                            \
    }                                                                         \
    PACKA(y0_, y1_, AH, AL);                                                  \
} while (0)

#define LOADB(KC, BH, BL) do {                                                \
    _Pragma("unroll")                                                         \
    for (int nt_ = 0; nt_ < 4; nt_++) {                                       \
        size_t off_ = ((size_t)((KC) * 16 + q * 4 + nt_) * 16 + mn) * 8;      \
        BH[nt_] = *(const bfrag*)(bhi + off_);                                \
        BL[nt_] = *(const bfrag*)(blo + off_);                                \
    }                                                                         \
} while (0)

#define MFMA3(AH, AL, BH, BL) do {                                            \
    _Pragma("unroll")                                                         \
    for (int nt_ = 0; nt_ < 4; nt_++) {                                       \
        acc[nt_] = __builtin_amdgcn_mfma_f32_16x16x32_bf16(AH, BH[nt_], acc[nt_], 0, 0, 0); \
        acc[nt_] = __builtin_amdgcn_mfma_f32_16x16x32_bf16(AH, BL[nt_], acc[nt_], 0, 0, 0); \
        acc[nt_] = __builtin_amdgcn_mfma_f32_16x16x32_bf16(AL, BH[nt_], acc[nt_], 0, 0, 0); \
    }                                                                         \
} while (0)

__global__ __launch_bounds__(512, 1) void k12_frontend(
    const float* __restrict__ x, const float* __restrict__ conv_w,
    const float* __restrict__ conv_b,
    const float* __restrict__ fc1_w, const float* __restrict__ fc1_b,
    const float* __restrict__ fc2_w, const float* __restrict__ fc2_b,
    const float* __restrict__ iw, const float* __restrict__ ib,
    const float* __restrict__ sc1, const float* __restrict__ sc0,
    const float* __restrict__ swe, const float* __restrict__ swp,
    const unsigned short* __restrict__ bhi,
    const unsigned short* __restrict__ blo, int use_bsp,
    float* __restrict__ wn_s, float* __restrict__ wd_s)
{
    // x tile: 16 samples x 2070 f = 33120 f = 132,480 B (fits 160 KB LDS).
    // After the K-loop (barrier), the same memory is reused as the epilogue
    // buffers (11,920 f needed <= 33,120 f available).
    __shared__ __align__(16) float smem[33120];
    float* redS = smem;            // [8][16][64] = 8192 f partial-C buffer
    float* hS   = smem + 8192;     // 16 x 68 = 1088 f
    float* w2S  = smem + 9312;     // [s][n] stride 65, 2080 f
    float* seqS = smem + 11392;    // [sample][s] stride 33, 528 f

    const int t    = threadIdx.x;   // 0..511
    const int b0   = blockIdx.x * 16;
    const int lane = t & 63;
    const int wv   = t >> 6;        // wave 0..7 -> K eighth
    const int q    = lane >> 4;     // quad -> channel pair 2q,2q+1
    const int mn   = lane & 15;     // sample (A) / out-within-tile (B)
    const int o0   = 2 * q;

    // ---- stage x tile: 8280 float4, perfectly coalesced linear copy ----
    {
        const float* xg = x + (size_t)b0 * 2070;
        #pragma unroll
        for (int i = 0; i < 16; i++) {
            int idx = i * 512 + t;
            fvec4 v;
            __builtin_memcpy(&v, xg + (size_t)idx * 4, 16);
            __builtin_memcpy(smem + (size_t)idx * 4, &v, 16);
        }
        if (t < 88) {               // tail: 8280 - 8192
            int idx = 8192 + t;
            fvec4 v;
            __builtin_memcpy(&v, xg + (size_t)idx * 4, 16);
            __builtin_memcpy(smem + (size_t)idx * 4, &v, 16);
        }
    }
    __syncthreads();

    // conv weights + bias for this lane's channel pair, in registers
    float cw0[12], cw1[12];
    #pragma unroll
    for (int i = 0; i < 12; i++) {
        cw0[i] = conv_w[o0 * 12 + i];
        cw1[i] = conv_w[o0 * 12 + 12 + i];
    }
    const float cb0 = conv_b[o0], cb1 = conv_b[o0 + 1];
    const float* xls = smem + mn * 2070;   // this lane's sample, in LDS

    ffrag acc[4];
    #pragma unroll
    for (int nt = 0; nt < 4; nt++) acc[nt] = (ffrag){0.f, 0.f, 0.f, 0.f};

    const int kc0 = wv * 20;

    // fast-path predicate: all 4 positions of chunk kc in one conv row
    auto isFast = [](int kc) {
        int r0 = kc * 4;
        int oh0 = (r0 * 565) >> 14;
        int ow0 = r0 - oh0 * 29;
        return (ow0 <= 25 && r0 + 3 <= 637);
    };

    if (use_bsp) {
        float winA[30], winB[30];
        bfrag bh0[4], bl0[4], bh1[4], bl1[4];
        bool fA = isFast(kc0);
        if (fA) LOADWIN(kc0, winA);
        LOADB(kc0, bh0, bl0);
        for (int kk = 0; kk < 20; kk += 2) {
            const int kc = kc0 + kk;
            // -- half 1: compute kc from winA/b0; prefetch kc+1 -> winB/b1 --
            bool fB = isFast(kc + 1);
            LOADB(kc + 1, bh1, bl1);
            if (fB) LOADWIN(kc + 1, winB);
            {
                bfrag a_hi, a_lo;
                if (fA) { BUILDA_FAST(winA, a_hi, a_lo); }
                else    { BUILDA_SLOW(kc, a_hi, a_lo); }
                MFMA3(a_hi, a_lo, bh0, bl0);
            }
            // -- half 2: compute kc+1 from winB/b1; prefetch kc+2 -> winA/b0 --
            fA = isFast(kc + 2);
            if (kk + 2 < 20) {
                LOADB(kc + 2, bh0, bl0);
                if (fA) LOADWIN(kc + 2, winA);
            }
            {
                bfrag a_hi, a_lo;
                if (fB) { BUILDA_FAST(winB, a_hi, a_lo); }
                else    { BUILDA_SLOW(kc + 1, a_hi, a_lo); }
                MFMA3(a_hi, a_lo, bh1, bl1);
            }
        }
    } else {
        // fallback: in-loop fp32 load + split (ws too small for pre-split B)
        for (int kk = 0; kk < 20; kk++) {
            const int kc = kc0 + kk;
            bfrag a_hi, a_lo;
            BUILDA_SLOW(kc, a_hi, a_lo);
            #pragma unroll
            for (int nt = 0; nt < 4; nt++) {
                int n = nt * 16 + mn;
                bfrag b_h, b_l;
                #pragma unroll
                for (int j = 0; j < 8; j++) {
                    int o = o0 + (j >> 2);
                    int r = kc * 4 + (j & 3);
                    float vv = (r < 638) ? fc1_w[(size_t)n * KTOT + o * 638 + r] : 0.f;
                    unsigned short h = bf_hi(vv);
                    b_h[j] = (short)h;
                    b_l[j] = (short)bf_hi(vv - __uint_as_float((unsigned)h << 16));
                }
                acc[nt] = __builtin_amdgcn_mfma_f32_16x16x32_bf16(a_hi, b_h, acc[nt], 0, 0, 0);
                acc[nt] = __builtin_amdgcn_mfma_f32_16x16x32_bf16(a_hi, b_l, acc[nt], 0, 0, 0);
                acc[nt] = __builtin_amdgcn_mfma_f32_16x16x32_bf16(a_lo, b_h, acc[nt], 0, 0, 0);
            }
        }
    }

    // all waves must be done READING the x tile before we overwrite it with
    // the epilogue buffers (smem aliasing).
    __syncthreads();

    // ---- cross-wave K reduction: 8 partials -> LDS -> sum + bias + ReLU ----
    // C/D layout: col = lane&15 -> n-within-tile, row = q*4 + reg -> m.
    #pragma unroll
    for (int nt = 0; nt < 4; nt++) {
        int n = nt * 16 + mn;
        #pragma unroll
        for (int rg = 0; rg < 4; rg++) {
            int m = q * 4 + rg;
            redS[(wv * 16 + m) * 64 + n] = acc[nt][rg];
        }
    }
    __syncthreads();
    #pragma unroll
    for (int e = 0; e < 2; e++) {
        int flat = e * 512 + t;           // 1024 = 16*64
        int m = flat >> 6, n = flat & 63;
        float s = 0.f;
        #pragma unroll
        for (int p = 0; p < 8; p++) s += redS[(p * 16 + m) * 64 + n];
        hS[m * 68 + n] = fmaxf(s + fc1_b[n], 0.f);
    }
    // ---- stage fc2 weights ----
    #pragma unroll
    for (int e = 0; e < 4; e++) {
        int flat = e * 512 + t;           // 2048 = 32*64
        int s = flat >> 6, n = flat & 63;
        w2S[s * 65 + n] = fc2_w[flat];
    }
    __syncthreads();

    // ---- fc2 + input affine -> seq (16 samples x 32 sensory = 512 items) ----
    {
        int s = t & 31, bl = t >> 5;
        float a2 = fc2_b[s];
        #pragma unroll 8
        for (int n = 0; n < 64; n++)
            a2 = fmaf(hS[bl * 68 + n], w2S[s * 65 + n], a2);
        seqS[bl * 33 + s] = a2 * iw[s] + ib[s];
    }
    __syncthreads();

    // ---- sensory synapse sums (16 samples x 19 neurons = 304 items) ----
    if (t < 304) {
        int n = t % 19, bl = t / 19;
        float wn = 0.f, wd = 0.f;
        #pragma unroll
        for (int s = 0; s < 32; s++) {
            float xx = sc0[s * 19 + n] - sc1[s * 19 + n] * seqS[bl * 33 + s];
            float ee = __builtin_amdgcn_exp2f(xx);
            float uu = __builtin_amdgcn_rcpf(1.f + ee);
            wn = fmaf(swe[s * 19 + n], uu, wn);
            wd = fmaf(swp[s * 19 + n], uu, wd);
        }
        wn_s[(b0 + bl) * 19 + n] = wn;
        wd_s[(b0 + bl) * 19 + n] = wd;
    }
}

// ---------------------------------------------------------------------------
// K3P v4 (R7-proven, measured-best scan: batched bpermute, p-split 10
// sigmoids/lane, permlane half_sum, tree sums, 1024x8). Scan search closed:
// batching was the one win (88->~74); TLP (77), readlane-19 (90),
// readlane-pair (82.7) all null/worse -> dep-chain + trans-issue bound.
// ---------------------------------------------------------------------------
__global__ __launch_bounds__(64, 1) void k3p2_scan(
    const float* __restrict__ wn_s, const float* __restrict__ wd_s,
    const float* __restrict__ rc1, const float* __restrict__ rc0,
    const float* __restrict__ rwe, const float* __restrict__ rwp,
    const float* __restrict__ neu,
    const float* __restrict__ out_w, const float* __restrict__ out_b,
    float* __restrict__ out)
{
    const int l    = threadIdx.x;       // 0..63
    const int col  = l & 31;            // target neuron (19 real + 13 pad)
    const int p    = l >> 5;            // source half
    const int cidx = (col < 19) ? col : 0;

    float ca[10], cb[10], cwe[10], cwp[10];
    int gidx[10];
    #pragma unroll
    for (int j = 0; j < 10; j++) {
        int s = p * 10 + j;
        bool e = (col < 19) && (s < 19);
        int idx = e ? (s * 19 + col) : 0;
        ca[j]  = e ? rc1[idx] : 0.f;
        cb[j]  = e ? rc0[idx] : 0.f;
        cwe[j] = e ? rwe[idx] : 0.f;
        cwp[j] = e ? rwp[idx] : 0.f;
        gidx[j] = ((s < 19) ? s : 0) * 4;
    }

    const float cmt  = neu[cidx];
    const float gvl  = neu[64 + cidx];
    const float den0 = neu[128 + cidx];
    const float owv  = out_w[0];
    const float obv  = out_b[0];

    const int c       = blockIdx.x;
    const int s_out   = c * S_PER;
    const int s_begin = (s_out > WARM) ? (s_out - WARM) : 0;
    const int s_end   = s_out + S_PER;

    float v = 0.f;
    float wnc = wn_s[s_begin * 19 + cidx];
    float wdc = wd_s[s_begin * 19 + cidx];

    for (int tt = s_begin; tt < s_end; tt++) {
        int nt = (tt + 1 < T_STEPS) ? (tt + 1) : (T_STEPS - 1);
        float wnn = wn_s[nt * 19 + cidx];
        float wdn = wd_s[nt * 19 + cidx];

        #pragma unroll
        for (int u = 0; u < 6; u++) {
            // ---- batched gather: issue all 10 bpermutes, then compute ----
            float vs[10];
            #pragma unroll
            for (int j = 0; j < 10; j++)
                vs[j] = __int_as_float(
                    __builtin_amdgcn_ds_bpermute(gidx[j], __float_as_int(v)));

            float tn[10], td[10];
            #pragma unroll
            for (int j = 0; j < 10; j++) {
                float xx = fmaf(-ca[j], vs[j], cb[j]);
                float ee = __builtin_amdgcn_exp2f(xx);
                float uu = __builtin_amdgcn_rcpf(1.f + ee);
                tn[j] = cwe[j] * uu;
                td[j] = cwp[j] * uu;
            }
            // tree sums (order change vs serial chain is within tolerance)
            float pn = (((tn[0] + tn[1]) + (tn[2] + tn[3]))
                      + ((tn[4] + tn[5]) + (tn[6] + tn[7])))
                      + (tn[8] + tn[9]);
            float pd = (((td[0] + td[1]) + (td[2] + td[3]))
                      + ((td[4] + td[5]) + (td[6] + td[7])))
                      + (td[8] + td[9]);

            // cross-half reduce, VALU-only
            pn = half_sum(pn);
            pd = half_sum(pd);

            float num = fmaf(cmt, v, gvl) + (pn + wnc);
            float den = den0 + pd + wdc;
            v = num * __builtin_amdgcn_rcpf(den);
        }
        if (l == 0 && tt >= s_out) out[tt] = fmaf(v, owv, obv);
        wnc = wnn; wdc = wdn;
    }
}

// ---------------------------------------------------------------------------
extern "C" void kernel_launch(void* const* d_in, const int* in_sizes, int n_in,
                              void* d_out, int out_size, void* d_ws, size_t ws_size,
                              hipStream_t stream) {
    const float* x      = (const float*)d_in[0];
    const float* conv_w = (const float*)d_in[1];
    const float* conv_b = (const float*)d_in[2];
    const float* fc1_w  = (const float*)d_in[3];
    const float* fc1_b  = (const float*)d_in[4];
    const float* fc2_w  = (const float*)d_in[5];
    const float* fc2_b  = (const float*)d_in[6];
    const float* iw     = (const float*)d_in[7];
    const float* ib     = (const float*)d_in[8];
    const float* sw     = (const float*)d_in[9];
    const float* smu    = (const float*)d_in[10];
    const float* ssig   = (const float*)d_in[11];
    const float* serev  = (const float*)d_in[12];
    const float* smask  = (const float*)d_in[13];
    const float* w      = (const float*)d_in[14];
    const float* mu     = (const float*)d_in[15];
    const float* sigma  = (const float*)d_in[16];
    const float* erev   = (const float*)d_in[17];
    const float* mask   = (const float*)d_in[18];
    const float* gleak  = (const float*)d_in[19];
    const float* vleak  = (const float*)d_in[20];
    const float* cm     = (const float*)d_in[21];
    const float* ow     = (const float*)d_in[22];
    const float* ob     = (const float*)d_in[23];

    float* ws   = (float*)d_ws;
    float* wn_s = ws;                    // 8192*19 = 155648
    float* wd_s = wn_s + 155648;         // 155648
    float* sc1  = wd_s + 155648;         // 640 each
    float* sc0  = sc1 + 640;
    float* swe  = sc0 + 640;
    float* swp  = swe + 640;
    float* rc1  = swp + 640;             // 384 each
    float* rc0  = rc1 + 384;
    float* rwe  = rc0 + 384;
    float* rwp  = rwe + 384;
    float* neu  = rwp + 384;             // 192  (base ends at 315,584 floats)
    const int use_bsp = (ws_size >= (size_t)WS_NEED_BSP) ? 1 : 0;
    unsigned short* bhi = (unsigned short*)(ws + WS_BASE_FLOATS);
    unsigned short* blo = bhi + 64 * KP;
    (void)in_sizes; (void)n_in; (void)out_size;

    hipLaunchKernelGGL(k0_combined, dim3(513), dim3(640), 0, stream,
        sw, smu, ssig, serev, smask, w, mu, sigma, erev, mask,
        gleak, vleak, cm, sc1, sc0, swe, swp, rc1, rc0, rwe, rwp, neu,
        fc1_w, bhi, blo, use_bsp);

    hipLaunchKernelGGL(k12_frontend, dim3(512), dim3(512), 0, stream,
        x, conv_w, conv_b, fc1_w, fc1_b, fc2_w, fc2_b, iw, ib,
        sc1, sc0, swe, swp, bhi, blo, use_bsp, wn_s, wd_s);

    hipLaunchKernelGGL(k3p2_scan, dim3(SCAN_CHUNKS), dim3(64), 0, stream,
        wn_s, wd_s, rc1, rc0, rwe, rwp, neu, ow, ob, (float*)d_out);
}

// Round 14
// 251.027 us; speedup vs baseline: 1.2849x; 1.0083x over previous
//
#include <hip/hip_runtime.h>
#include <hip/hip_bf16.h>
#include <math.h>

#define L2E 1.4426950408889634f
#define T_STEPS 8192
#define KTOT 5104   // 8 channels * 638 spatial (22*29)
#define EPS_LTC 1e-8f
#define KP 5120     // permuted/padded K (160 chunks x 32)

// scan chunking: 1024 chunks x 8 steps, 16-step burn-in (chunks 0,1 exact).
#define SCAN_CHUNKS 1024
#define S_PER  8
#define WARM   16

// ws layout (floats): base 315,584 f = 1,262,336 B; optional pre-split B adds
// 2 x 327,680 ushorts = 1,310,720 B  ->  total 2,573,056 B (gated on ws_size).
#define WS_BASE_FLOATS 315584
#define WS_NEED_BSP    2573056

typedef __attribute__((ext_vector_type(8))) short bfrag;   // 8 bf16 (4 VGPR)
typedef __attribute__((ext_vector_type(4))) float ffrag;   // 4 fp32 acc
typedef __attribute__((ext_vector_type(4))) float fvec4;

__device__ __forceinline__ float softplus_f(float x) {
    return log1pf(expf(-fabsf(x))) + fmaxf(x, 0.f);
}

__device__ __forceinline__ unsigned short bf_hi(float f) {  // RNE fp32->bf16
    unsigned u = __float_as_uint(f);
    u = u + 0x7FFFu + ((u >> 16) & 1u);
    return (unsigned short)(u >> 16);
}

__device__ __forceinline__ float elu_f(float x) {
    return (x > 0.f) ? x : (__builtin_amdgcn_exp2f(x * L2E) - 1.f);
}

// cross-half (lane i <-> lane i+32) sum without LDS: v_permlane32_swap is a
// VALU op (~8 cy) vs ds_bpermute (~120 cy exposed at low occupancy).
__device__ __forceinline__ float half_sum(float x) {
#if __has_builtin(__builtin_amdgcn_permlane32_swap)
    auto r = __builtin_amdgcn_permlane32_swap(__float_as_int(x), __float_as_int(x),
                                              false, false);
    return __int_as_float(r[0]) + __int_as_float(r[1]);
#else
    int pidx = ((threadIdx.x & 63) ^ 32) * 4;
    return x + __int_as_float(
        __builtin_amdgcn_ds_bpermute(pidx, __float_as_int(x)));
#endif
}

// ---------------------------------------------------------------------------
// K0C: combined param precompute + fc1_w pre-split (one launch instead of
// two). Blocks 0..511: splitB (gather form — R7-proven). Block 512: params.
// ---------------------------------------------------------------------------
__global__ __launch_bounds__(640) void k0_combined(
    const float* __restrict__ sw, const float* __restrict__ smu,
    const float* __restrict__ ssig, const float* __restrict__ serev,
    const float* __restrict__ smask,
    const float* __restrict__ w, const float* __restrict__ mu,
    const float* __restrict__ sigma, const float* __restrict__ erev,
    const float* __restrict__ mask,
    const float* __restrict__ gleak, const float* __restrict__ vleak,
    const float* __restrict__ cm,
    float* __restrict__ sc1, float* __restrict__ sc0,
    float* __restrict__ swe, float* __restrict__ swp,
    float* __restrict__ rc1, float* __restrict__ rc0,
    float* __restrict__ rwe, float* __restrict__ rwp,
    float* __restrict__ neu,
    const float* __restrict__ fc1_w,
    unsigned short* __restrict__ bhi, unsigned short* __restrict__ blo,
    int use_bsp)
{
    if (blockIdx.x == 512) {
        int t = threadIdx.x;
        if (t < 608) {   // sensory (32 x 19)
            float sp = softplus_f(sw[t]);
            float c1 = ssig[t] * L2E;
            sc1[t] = c1;
            sc0[t] = c1 * smu[t];
            swe[t] = sp * serev[t];
            swp[t] = sp * smask[t];
        }
        if (t < 361) {   // recurrent (19 x 19), layout [src*19 + tgt]
            float wp = softplus_f(w[t]) * mask[t];
            float c1 = sigma[t] * L2E;
            rc1[t] = c1;
            rc0[t] = c1 * mu[t];
            rwe[t] = wp * erev[t];
            rwp[t] = wp;
        }
        if (t < 64) {
            if (t < 19) {
                float g   = softplus_f(gleak[t]);
                float cmt = softplus_f(cm[t]) * 6.f;   // ODE_UNFOLDS
                neu[t]       = cmt;
                neu[64 + t]  = g * vleak[t];
                neu[128 + t] = cmt + g + EPS_LTC;
            } else {
                neu[t] = 0.f; neu[64 + t] = 0.f; neu[128 + t] = 1.f;
            }
        }
        return;
    }
    if (!use_bsp) return;
    // splitB: fragment-interleaved bf16 hi/lo of fc1_w.
    int g = blockIdx.x * 640 + threadIdx.x;   // 0 .. 64*KP-1
    int j  = g & 7;
    int mn = (g >> 3) & 15;
    int nt = (g >> 7) & 3;
    int q  = (g >> 9) & 3;
    int kc = g >> 11;
    int n  = nt * 16 + mn;
    int o  = 2 * q + (j >> 2);
    int r  = kc * 4 + (j & 3);
    float v = (r < 638) ? fc1_w[n * KTOT + o * 638 + r] : 0.f;
    unsigned short h = bf_hi(v);
    bhi[g] = h;
    blo[g] = bf_hi(v - __uint_as_float((unsigned)h << 16));
}

// ---------------------------------------------------------------------------
// K12 v18: v16 (R7-proven) + global_load_lds staging.
//  The x-tile staging is a barricaded serial phase (all 8 waves blocked on
//  it, twice per CU over the 2 dispatch rounds). v16 stages via VGPR
//  round-trip (17 global_load_dwordx4 + 17 ds_write_b128 per thread).
//  Fix (guide Common-mistake #1, m97: width-16 DMA = +67% on staging):
//  __builtin_amdgcn_global_load_lds(.., 16, ..) — our layout is exactly
//  the required wave-uniform-LDS-base + lane*16B pattern (idx = i*512+t,
//  linear). Tail (t<88) is exec-masked. Same bytes, same order -> zero
//  numerical change. Fallback to memcpy path if builtin unavailable.
//  Everything else byte-identical to v16 (75-82 us, VGPR 120, no spill).
// ---------------------------------------------------------------------------
#define LOADWIN(KC, WB) do {                                                  \
    int r0_  = (KC) * 4;                                                      \
    int oh0_ = (r0_ * 565) >> 14;                                             \
    int ow0_ = r0_ - oh0_ * 29;                                               \
    _Pragma("unroll")                                                         \
    for (int cc_ = 0; cc_ < 3; cc_++) {                                       \
        const float* a0_ = xls + cc_ * 690 + oh0_ * 30 + ow0_;                \
        fvec4 v0_, v1_;                                                       \
        __builtin_memcpy(&v0_, a0_, 16);                                      \
        __builtin_memcpy(&v1_, a0_ + 30, 16);                                 \
        WB[cc_*10+0]=v0_.x; WB[cc_*10+1]=v0_.y; WB[cc_*10+2]=v0_.z;           \
        WB[cc_*10+3]=v0_.w; WB[cc_*10+4]=a0_[4];                              \
        WB[cc_*10+5]=v1_.x; WB[cc_*10+6]=v1_.y; WB[cc_*10+7]=v1_.z;           \
        WB[cc_*10+8]=v1_.w; WB[cc_*10+9]=a0_[34];                             \
    }                                                                         \
} while (0)

#define PACKA(Y0, Y1, AH, AL) do {                                            \
    _Pragma("unroll")                                                         \
    for (int j_ = 0; j_ < 4; j_++) {                                          \
        unsigned short h0_ = bf_hi(Y0[j_]);                                   \
        AH[j_] = (short)h0_;                                                  \
        AL[j_] = (short)bf_hi(Y0[j_] - __uint_as_float((unsigned)h0_ << 16)); \
        unsigned short h1_ = bf_hi(Y1[j_]);                                   \
        AH[4+j_] = (short)h1_;                                                \
        AL[4+j_] = (short)bf_hi(Y1[j_] - __uint_as_float((unsigned)h1_ << 16));\
    }                                                                         \
} while (0)

#define BUILDA_FAST(WB, AH, AL) do {                                          \
    float y0_[4], y1_[4];                                                     \
    _Pragma("unroll")                                                         \
    for (int rr_ = 0; rr_ < 4; rr_++) {                                       \
        float a0v_ = cb0, a1v_ = cb1;                                         \
        _Pragma("unroll")                                                     \
        for (int cc_ = 0; cc_ < 3; cc_++) {                                   \
            float x00_ = WB[cc_*10+rr_],   x01_ = WB[cc_*10+rr_+1];           \
            float x10_ = WB[cc_*10+5+rr_], x11_ = WB[cc_*10+6+rr_];           \
            a0v_ = fmaf(x00_, cw0[cc_*4+0], a0v_);                            \
            a0v_ = fmaf(x01_, cw0[cc_*4+1], a0v_);                            \
            a0v_ = fmaf(x10_, cw0[cc_*4+2], a0v_);                            \
            a0v_ = fmaf(x11_, cw0[cc_*4+3], a0v_);                            \
            a1v_ = fmaf(x00_, cw1[cc_*4+0], a1v_);                            \
            a1v_ = fmaf(x01_, cw1[cc_*4+1], a1v_);                            \
            a1v_ = fmaf(x10_, cw1[cc_*4+2], a1v_);                            \
            a1v_ = fmaf(x11_, cw1[cc_*4+3], a1v_);                            \
        }                                                                     \
        y0_[rr_] = elu_f(a0v_);                                               \
        y1_[rr_] = elu_f(a1v_);                                               \
    }                                                                         \
    PACKA(y0_, y1_, AH, AL);                                                  \
} while (0)

#define BUILDA_SLOW(KC, AH, AL) do {                                          \
    float y0_[4], y1_[4];                                                     \
    int r0_ = (KC) * 4;                                                       \
    _Pragma("unroll")                                                         \
    for (int rr_ = 0; rr_ < 4; rr_++) {                                       \
        int r_ = r0_ + rr_;                                                   \
        if (r_ < 638) {                                                       \
            int oh_ = (r_ * 565) >> 14;                                       \
            const float* xp_ = xls + oh_ * 30 + (r_ - oh_ * 29);              \
            float a0v_ = cb0, a1v_ = cb1;                                     \
            _Pragma("unroll")                                                 \
            for (int cc_ = 0; cc_ < 3; cc_++) {                               \
                float x00_ = xp_[cc_*690],    x01_ = xp_[cc_*690+1];          \
                float x10_ = xp_[cc_*690+30], x11_ = xp_[cc_*690+31];         \
                a0v_ = fmaf(x00_, cw0[cc_*4+0], a0v_);                        \
                a0v_ = fmaf(x01_, cw0[cc_*4+1], a0v_);                        \
                a0v_ = fmaf(x10_, cw0[cc_*4+2], a0v_);                        \
                a0v_ = fmaf(x11_, cw0[cc_*4+3], a0v_);                        \
                a1v_ = fmaf(x00_, cw1[cc_*4+0], a1v_);                        \
                a1v_ = fmaf(x01_, cw1[cc_*4+1], a1v_);                        \
                a1v_ = fmaf(x10_, cw1[cc_*4+2], a1v_);                        \
                a1v_ = fmaf(x11_, cw1[cc_*4+3], a1v_);                        \
            }                                                                 \
            y0_[rr_] = elu_f(a0v_);                                           \
            y1_[rr_] = elu_f(a1v_);                                           \
        } else { y0_[rr_] = 0.f; y1_[rr_] = 0.f; }                            \
    }                                                                         \
    PACKA(y0_, y1_, AH, AL);                                                  \
} while (0)

#define LOADB(KC, BH, BL) do {                                                \
    _Pragma("unroll")                                                         \
    for (int nt_ = 0; nt_ < 4; nt_++) {                                       \
        size_t off_ = ((size_t)((KC) * 16 + q * 4 + nt_) * 16 + mn) * 8;      \
        BH[nt_] = *(const bfrag*)(bhi + off_);                                \
        BL[nt_] = *(const bfrag*)(blo + off_);                                \
    }                                                                         \
} while (0)

#define MFMA3(AH, AL, BH, BL) do {                                            \
    _Pragma("unroll")                                                         \
    for (int nt_ = 0; nt_ < 4; nt_++) {                                       \
        acc[nt_] = __builtin_amdgcn_mfma_f32_16x16x32_bf16(AH, BH[nt_], acc[nt_], 0, 0, 0); \
        acc[nt_] = __builtin_amdgcn_mfma_f32_16x16x32_bf16(AH, BL[nt_], acc[nt_], 0, 0, 0); \
        acc[nt_] = __builtin_amdgcn_mfma_f32_16x16x32_bf16(AL, BH[nt_], acc[nt_], 0, 0, 0); \
    }                                                                         \
} while (0)

__global__ __launch_bounds__(512, 1) void k12_frontend(
    const float* __restrict__ x, const float* __restrict__ conv_w,
    const float* __restrict__ conv_b,
    const float* __restrict__ fc1_w, const float* __restrict__ fc1_b,
    const float* __restrict__ fc2_w, const float* __restrict__ fc2_b,
    const float* __restrict__ iw, const float* __restrict__ ib,
    const float* __restrict__ sc1, const float* __restrict__ sc0,
    const float* __restrict__ swe, const float* __restrict__ swp,
    const unsigned short* __restrict__ bhi,
    const unsigned short* __restrict__ blo, int use_bsp,
    float* __restrict__ wn_s, float* __restrict__ wd_s)
{
    // x tile: 16 samples x 2070 f = 33120 f = 132,480 B (fits 160 KB LDS).
    // After the K-loop (barrier), the same memory is reused as the epilogue
    // buffers (11,920 f needed <= 33,120 f available).
    __shared__ __align__(16) float smem[33120];
    float* redS = smem;            // [8][16][64] = 8192 f partial-C buffer
    float* hS   = smem + 8192;     // 16 x 68 = 1088 f
    float* w2S  = smem + 9312;     // [s][n] stride 65, 2080 f
    float* seqS = smem + 11392;    // [sample][s] stride 33, 528 f

    const int t    = threadIdx.x;   // 0..511
    const int b0   = blockIdx.x * 16;
    const int lane = t & 63;
    const int wv   = t >> 6;        // wave 0..7 -> K eighth
    const int q    = lane >> 4;     // quad -> channel pair 2q,2q+1
    const int mn   = lane & 15;     // sample (A) / out-within-tile (B)
    const int o0   = 2 * q;

    // ---- stage x tile: 8280 16B-chunks, linear copy ----
    // layout matches global_load_lds exactly: per-wave LDS dest =
    // wave-uniform base + lane*16B; per-lane global src.
    {
        const float* xg = x + (size_t)b0 * 2070;
#if __has_builtin(__builtin_amdgcn_global_load_lds)
        #pragma unroll
        for (int i = 0; i < 16; i++) {
            int idx = i * 512 + t;
            __builtin_amdgcn_global_load_lds(
                (const __attribute__((address_space(1))) unsigned int*)(xg + (size_t)idx * 4),
                (__attribute__((address_space(3))) unsigned int*)(smem + (size_t)idx * 4),
                16, 0, 0);
        }
        if (t < 88) {               // tail: 8280 - 8192 (exec-masked lanes)
            int idx = 8192 + t;
            __builtin_amdgcn_global_load_lds(
                (const __attribute__((address_space(1))) unsigned int*)(xg + (size_t)idx * 4),
                (__attribute__((address_space(3))) unsigned int*)(smem + (size_t)idx * 4),
                16, 0, 0);
        }
#else
        #pragma unroll
        for (int i = 0; i < 16; i++) {
            int idx = i * 512 + t;
            fvec4 v;
            __builtin_memcpy(&v, xg + (size_t)idx * 4, 16);
            __builtin_memcpy(smem + (size_t)idx * 4, &v, 16);
        }
        if (t < 88) {               // tail: 8280 - 8192
            int idx = 8192 + t;
            fvec4 v;
            __builtin_memcpy(&v, xg + (size_t)idx * 4, 16);
            __builtin_memcpy(smem + (size_t)idx * 4, &v, 16);
        }
#endif
    }
    __syncthreads();   // compiler emits s_waitcnt vmcnt(0) before s_barrier

    // conv weights + bias for this lane's channel pair, in registers
    float cw0[12], cw1[12];
    #pragma unroll
    for (int i = 0; i < 12; i++) {
        cw0[i] = conv_w[o0 * 12 + i];
        cw1[i] = conv_w[o0 * 12 + 12 + i];
    }
    const float cb0 = conv_b[o0], cb1 = conv_b[o0 + 1];
    const float* xls = smem + mn * 2070;   // this lane's sample, in LDS

    ffrag acc[4];
    #pragma unroll
    for (int nt = 0; nt < 4; nt++) acc[nt] = (ffrag){0.f, 0.f, 0.f, 0.f};

    const int kc0 = wv * 20;

    // fast-path predicate: all 4 positions of chunk kc in one conv row
    auto isFast = [](int kc) {
        int r0 = kc * 4;
        int oh0 = (r0 * 565) >> 14;
        int ow0 = r0 - oh0 * 29;
        return (ow0 <= 25 && r0 + 3 <= 637);
    };

    if (use_bsp) {
        float winA[30], winB[30];
        bfrag bh0[4], bl0[4], bh1[4], bl1[4];
        bool fA = isFast(kc0);
        if (fA) LOADWIN(kc0, winA);
        LOADB(kc0, bh0, bl0);
        for (int kk = 0; kk < 20; kk += 2) {
            const int kc = kc0 + kk;
            // -- half 1: compute kc from winA/b0; prefetch kc+1 -> winB/b1 --
            bool fB = isFast(kc + 1);
            LOADB(kc + 1, bh1, bl1);
            if (fB) LOADWIN(kc + 1, winB);
            {
                bfrag a_hi, a_lo;
                if (fA) { BUILDA_FAST(winA, a_hi, a_lo); }
                else    { BUILDA_SLOW(kc, a_hi, a_lo); }
                MFMA3(a_hi, a_lo, bh0, bl0);
            }
            // -- half 2: compute kc+1 from winB/b1; prefetch kc+2 -> winA/b0 --
            fA = isFast(kc + 2);
            if (kk + 2 < 20) {
                LOADB(kc + 2, bh0, bl0);
                if (fA) LOADWIN(kc + 2, winA);
            }
            {
                bfrag a_hi, a_lo;
                if (fB) { BUILDA_FAST(winB, a_hi, a_lo); }
                else    { BUILDA_SLOW(kc + 1, a_hi, a_lo); }
                MFMA3(a_hi, a_lo, bh1, bl1);
            }
        }
    } else {
        // fallback: in-loop fp32 load + split (ws too small for pre-split B)
        for (int kk = 0; kk < 20; kk++) {
            const int kc = kc0 + kk;
            bfrag a_hi, a_lo;
            BUILDA_SLOW(kc, a_hi, a_lo);
            #pragma unroll
            for (int nt = 0; nt < 4; nt++) {
                int n = nt * 16 + mn;
                bfrag b_h, b_l;
                #pragma unroll
                for (int j = 0; j < 8; j++) {
                    int o = o0 + (j >> 2);
                    int r = kc * 4 + (j & 3);
                    float vv = (r < 638) ? fc1_w[(size_t)n * KTOT + o * 638 + r] : 0.f;
                    unsigned short h = bf_hi(vv);
                    b_h[j] = (short)h;
                    b_l[j] = (short)bf_hi(vv - __uint_as_float((unsigned)h << 16));
                }
                acc[nt] = __builtin_amdgcn_mfma_f32_16x16x32_bf16(a_hi, b_h, acc[nt], 0, 0, 0);
                acc[nt] = __builtin_amdgcn_mfma_f32_16x16x32_bf16(a_hi, b_l, acc[nt], 0, 0, 0);
                acc[nt] = __builtin_amdgcn_mfma_f32_16x16x32_bf16(a_lo, b_h, acc[nt], 0, 0, 0);
            }
        }
    }

    // all waves must be done READING the x tile before we overwrite it with
    // the epilogue buffers (smem aliasing).
    __syncthreads();

    // ---- cross-wave K reduction: 8 partials -> LDS -> sum + bias + ReLU ----
    // C/D layout: col = lane&15 -> n-within-tile, row = q*4 + reg -> m.
    #pragma unroll
    for (int nt = 0; nt < 4; nt++) {
        int n = nt * 16 + mn;
        #pragma unroll
        for (int rg = 0; rg < 4; rg++) {
            int m = q * 4 + rg;
            redS[(wv * 16 + m) * 64 + n] = acc[nt][rg];
        }
    }
    __syncthreads();
    #pragma unroll
    for (int e = 0; e < 2; e++) {
        int flat = e * 512 + t;           // 1024 = 16*64
        int m = flat >> 6, n = flat & 63;
        float s = 0.f;
        #pragma unroll
        for (int p = 0; p < 8; p++) s += redS[(p * 16 + m) * 64 + n];
        hS[m * 68 + n] = fmaxf(s + fc1_b[n], 0.f);
    }
    // ---- stage fc2 weights ----
    #pragma unroll
    for (int e = 0; e < 4; e++) {
        int flat = e * 512 + t;           // 2048 = 32*64
        int s = flat >> 6, n = flat & 63;
        w2S[s * 65 + n] = fc2_w[flat];
    }
    __syncthreads();

    // ---- fc2 + input affine -> seq (16 samples x 32 sensory = 512 items) ----
    {
        int s = t & 31, bl = t >> 5;
        float a2 = fc2_b[s];
        #pragma unroll 8
        for (int n = 0; n < 64; n++)
            a2 = fmaf(hS[bl * 68 + n], w2S[s * 65 + n], a2);
        seqS[bl * 33 + s] = a2 * iw[s] + ib[s];
    }
    __syncthreads();

    // ---- sensory synapse sums (16 samples x 19 neurons = 304 items) ----
    if (t < 304) {
        int n = t % 19, bl = t / 19;
        float wn = 0.f, wd = 0.f;
        #pragma unroll
        for (int s = 0; s < 32; s++) {
            float xx = sc0[s * 19 + n] - sc1[s * 19 + n] * seqS[bl * 33 + s];
            float ee = __builtin_amdgcn_exp2f(xx);
            float uu = __builtin_amdgcn_rcpf(1.f + ee);
            wn = fmaf(swe[s * 19 + n], uu, wn);
            wd = fmaf(swp[s * 19 + n], uu, wd);
        }
        wn_s[(b0 + bl) * 19 + n] = wn;
        wd_s[(b0 + bl) * 19 + n] = wd;
    }
}

// ---------------------------------------------------------------------------
// K3P v4 (R7-proven, measured-best scan: batched bpermute, p-split 10
// sigmoids/lane, permlane half_sum, tree sums, 1024x8). Scan search closed:
// batching was the one win (88->~74); TLP (77), readlane-19 (90),
// readlane-pair (82.7) all null/worse -> dep-chain + trans-issue bound.
// ---------------------------------------------------------------------------
__global__ __launch_bounds__(64, 1) void k3p2_scan(
    const float* __restrict__ wn_s, const float* __restrict__ wd_s,
    const float* __restrict__ rc1, const float* __restrict__ rc0,
    const float* __restrict__ rwe, const float* __restrict__ rwp,
    const float* __restrict__ neu,
    const float* __restrict__ out_w, const float* __restrict__ out_b,
    float* __restrict__ out)
{
    const int l    = threadIdx.x;       // 0..63
    const int col  = l & 31;            // target neuron (19 real + 13 pad)
    const int p    = l >> 5;            // source half
    const int cidx = (col < 19) ? col : 0;

    float ca[10], cb[10], cwe[10], cwp[10];
    int gidx[10];
    #pragma unroll
    for (int j = 0; j < 10; j++) {
        int s = p * 10 + j;
        bool e = (col < 19) && (s < 19);
        int idx = e ? (s * 19 + col) : 0;
        ca[j]  = e ? rc1[idx] : 0.f;
        cb[j]  = e ? rc0[idx] : 0.f;
        cwe[j] = e ? rwe[idx] : 0.f;
        cwp[j] = e ? rwp[idx] : 0.f;
        gidx[j] = ((s < 19) ? s : 0) * 4;
    }

    const float cmt  = neu[cidx];
    const float gvl  = neu[64 + cidx];
    const float den0 = neu[128 + cidx];
    const float owv  = out_w[0];
    const float obv  = out_b[0];

    const int c       = blockIdx.x;
    const int s_out   = c * S_PER;
    const int s_begin = (s_out > WARM) ? (s_out - WARM) : 0;
    const int s_end   = s_out + S_PER;

    float v = 0.f;
    float wnc = wn_s[s_begin * 19 + cidx];
    float wdc = wd_s[s_begin * 19 + cidx];

    for (int tt = s_begin; tt < s_end; tt++) {
        int nt = (tt + 1 < T_STEPS) ? (tt + 1) : (T_STEPS - 1);
        float wnn = wn_s[nt * 19 + cidx];
        float wdn = wd_s[nt * 19 + cidx];

        #pragma unroll
        for (int u = 0; u < 6; u++) {
            // ---- batched gather: issue all 10 bpermutes, then compute ----
            float vs[10];
            #pragma unroll
            for (int j = 0; j < 10; j++)
                vs[j] = __int_as_float(
                    __builtin_amdgcn_ds_bpermute(gidx[j], __float_as_int(v)));

            float tn[10], td[10];
            #pragma unroll
            for (int j = 0; j < 10; j++) {
                float xx = fmaf(-ca[j], vs[j], cb[j]);
                float ee = __builtin_amdgcn_exp2f(xx);
                float uu = __builtin_amdgcn_rcpf(1.f + ee);
                tn[j] = cwe[j] * uu;
                td[j] = cwp[j] * uu;
            }
            // tree sums (order change vs serial chain is within tolerance)
            float pn = (((tn[0] + tn[1]) + (tn[2] + tn[3]))
                      + ((tn[4] + tn[5]) + (tn[6] + tn[7])))
                      + (tn[8] + tn[9]);
            float pd = (((td[0] + td[1]) + (td[2] + td[3]))
                      + ((td[4] + td[5]) + (td[6] + td[7])))
                      + (td[8] + td[9]);

            // cross-half reduce, VALU-only
            pn = half_sum(pn);
            pd = half_sum(pd);

            float num = fmaf(cmt, v, gvl) + (pn + wnc);
            float den = den0 + pd + wdc;
            v = num * __builtin_amdgcn_rcpf(den);
        }
        if (l == 0 && tt >= s_out) out[tt] = fmaf(v, owv, obv);
        wnc = wnn; wdc = wdn;
    }
}

// ---------------------------------------------------------------------------
extern "C" void kernel_launch(void* const* d_in, const int* in_sizes, int n_in,
                              void* d_out, int out_size, void* d_ws, size_t ws_size,
                              hipStream_t stream) {
    const float* x      = (const float*)d_in[0];
    const float* conv_w = (const float*)d_in[1];
    const float* conv_b = (const float*)d_in[2];
    const float* fc1_w  = (const float*)d_in[3];
    const float* fc1_b  = (const float*)d_in[4];
    const float* fc2_w  = (const float*)d_in[5];
    const float* fc2_b  = (const float*)d_in[6];
    const float* iw     = (const float*)d_in[7];
    const float* ib     = (const float*)d_in[8];
    const float* sw     = (const float*)d_in[9];
    const float* smu    = (const float*)d_in[10];
    const float* ssig   = (const float*)d_in[11];
    const float* serev  = (const float*)d_in[12];
    const float* smask  = (const float*)d_in[13];
    const float* w      = (const float*)d_in[14];
    const float* mu     = (const float*)d_in[15];
    const float* sigma  = (const float*)d_in[16];
    const float* erev   = (const float*)d_in[17];
    const float* mask   = (const float*)d_in[18];
    const float* gleak  = (const float*)d_in[19];
    const float* vleak  = (const float*)d_in[20];
    const float* cm     = (const float*)d_in[21];
    const float* ow     = (const float*)d_in[22];
    const float* ob     = (const float*)d_in[23];

    float* ws   = (float*)d_ws;
    float* wn_s = ws;                    // 8192*19 = 155648
    float* wd_s = wn_s + 155648;         // 155648
    float* sc1  = wd_s + 155648;         // 640 each
    float* sc0  = sc1 + 640;
    float* swe  = sc0 + 640;
    float* swp  = swe + 640;
    float* rc1  = swp + 640;             // 384 each
    float* rc0  = rc1 + 384;
    float* rwe  = rc0 + 384;
    float* rwp  = rwe + 384;
    float* neu  = rwp + 384;             // 192  (base ends at 315,584 floats)
    const int use_bsp = (ws_size >= (size_t)WS_NEED_BSP) ? 1 : 0;
    unsigned short* bhi = (unsigned short*)(ws + WS_BASE_FLOATS);
    unsigned short* blo = bhi + 64 * KP;
    (void)in_sizes; (void)n_in; (void)out_size;

    hipLaunchKernelGGL(k0_combined, dim3(513), dim3(640), 0, stream,
        sw, smu, ssig, serev, smask, w, mu, sigma, erev, mask,
        gleak, vleak, cm, sc1, sc0, swe, swp, rc1, rc0, rwe, rwp, neu,
        fc1_w, bhi, blo, use_bsp);

    hipLaunchKernelGGL(k12_frontend, dim3(512), dim3(512), 0, stream,
        x, conv_w, conv_b, fc1_w, fc1_b, fc2_w, fc2_b, iw, ib,
        sc1, sc0, swe, swp, bhi, blo, use_bsp, wn_s, wd_s);

    hipLaunchKernelGGL(k3p2_scan, dim3(SCAN_CHUNKS), dim3(64), 0, stream,
        wn_s, wd_s, rc1, rc0, rwe, rwp, neu, ow, ob, (float*)d_out);
}